// Round 2
// baseline (260.733 us; speedup 1.0000x reference)
//
#include <hip/hip_runtime.h>
#include <hip/hip_fp16.h>

#define N_NODES 50000
#define N_EDGES 800000
#define D_IN 128
#define D_HID 256
#define D_OUT 128
#define NCHUNK 196   // ceil(N_NODES / 256)
#define NTILES 3125  // N_NODES / 16 exact
#define FUSED_GRID 256

typedef _Float16 f16x8 __attribute__((ext_vector_type(8)));
typedef float f32x4 __attribute__((ext_vector_type(4)));

// ---------------- fused prep: zero_deg + cvt x + cvt weights ------------------
// 16B/lane vectorized: blocks [0,3125): xb; [3125,3141): 4 weight mats;
// [3141,3337): zero deg.

__device__ __forceinline__ void cvt8(const float* __restrict__ src,
                                     __half* __restrict__ dstp, int i) {
    const float4* s4 = (const float4*)src;
    float4 a = s4[i * 2];
    float4 b = s4[i * 2 + 1];
    float4 o;
    __half2* op = (__half2*)&o;
    op[0] = __float22half2_rn(make_float2(a.x, a.y));
    op[1] = __float22half2_rn(make_float2(a.z, a.w));
    op[2] = __float22half2_rn(make_float2(b.x, b.y));
    op[3] = __float22half2_rn(make_float2(b.z, b.w));
    ((float4*)dstp)[i] = o;
}

__global__ __launch_bounds__(256)
void prep_kernel(const float* __restrict__ x, __half* __restrict__ xb,
                 const float* __restrict__ Wl1, const float* __restrict__ Wr1,
                 const float* __restrict__ Wl2, const float* __restrict__ Wr2,
                 __half* __restrict__ wl1h, __half* __restrict__ wr1h,
                 __half* __restrict__ wl2h, __half* __restrict__ wr2h,
                 int* __restrict__ deg) {
    int b = blockIdx.x;
    if (b < 3125) {
        int i = b * 256 + threadIdx.x;            // 800000 threads x 8 floats
        cvt8(x, xb, i);
    } else if (b < 3141) {
        int i = (b - 3125) * 256 + threadIdx.x;   // 4096 threads x 8 floats/mat
        cvt8(Wl1, wl1h, i);
        cvt8(Wr1, wr1h, i);
        cvt8(Wl2, wl2h, i);
        cvt8(Wr2, wr2h, i);
    } else {
        int i = (b - 3141) * 256 + threadIdx.x;
        if (i < N_NODES) deg[i] = 0;
    }
}

// ---------------- CSR build: rank-split (atomic pass separated from scatter) --

__global__ void deg_rank_kernel(const int* __restrict__ dst, int* __restrict__ deg,
                                int* __restrict__ rank) {
    int i = blockIdx.x * blockDim.x + threadIdx.x;
    if (i < N_EDGES) rank[i] = atomicAdd(&deg[dst[i]], 1);
}

__global__ void chunk_sum(const int* __restrict__ deg, int* __restrict__ partial) {
    __shared__ int s[256];
    int i = blockIdx.x * 256 + threadIdx.x;
    s[threadIdx.x] = (i < N_NODES) ? deg[i] : 0;
    __syncthreads();
    for (int off = 128; off > 0; off >>= 1) {
        if (threadIdx.x < off) s[threadIdx.x] += s[threadIdx.x + off];
        __syncthreads();
    }
    if (threadIdx.x == 0) partial[blockIdx.x] = s[0];
}

// Per-chunk scan with integrated cross-chunk base.
__global__ void scatter_scan(const int* __restrict__ deg, const int* __restrict__ partial,
                             int* __restrict__ row_ptr, float* __restrict__ deg_inv) {
    __shared__ int s[256];
    __shared__ int base_s;
    const int tid = threadIdx.x;
    const int bid = blockIdx.x;
    s[tid] = (tid < bid) ? partial[tid] : 0;
    __syncthreads();
    for (int off = 128; off > 0; off >>= 1) {
        if (tid < off) s[tid] += s[tid + off];
        __syncthreads();
    }
    if (tid == 0) base_s = s[0];
    __syncthreads();
    int i = bid * 256 + tid;
    int v = (i < N_NODES) ? deg[i] : 0;
    s[tid] = v;
    __syncthreads();
    for (int off = 1; off < 256; off <<= 1) {
        int t = (tid >= off) ? s[tid - off] : 0;
        __syncthreads();
        s[tid] += t;
        __syncthreads();
    }
    if (i < N_NODES) {
        int rp = base_s + s[tid] - v;   // exclusive scan value
        row_ptr[i] = rp;
        deg_inv[i] = 1.0f / fmaxf((float)v, 1.0f);
        if (i == N_NODES - 1) row_ptr[N_NODES] = N_EDGES;
    }
}

// Atomic-free scatter: position = row_ptr[dst] + rank.
__global__ void fill_csr(const int* __restrict__ src, const int* __restrict__ dst,
                         const int* __restrict__ rank, const int* __restrict__ row_ptr,
                         int* __restrict__ csr_src) {
    int e = blockIdx.x * blockDim.x + threadIdx.x;
    if (e < N_EDGES) {
        csr_src[row_ptr[dst[e]] + rank[e]] = src[e];
    }
}

// ---------------- shared gather helpers --------------------------------------

__device__ __forceinline__ void add_row(const float4& v, float2 (&acc)[4]) {
    const __half2* hp = (const __half2*)&v;
    #pragma unroll
    for (int j = 0; j < 4; ++j) {
        float2 f = __half22float2(hp[j]);
        acc[j].x += f.x;
        acc[j].y += f.y;
    }
}

// ---------------- standalone gather (layer-2 aggregation: out += mean(P)) ----
// coalesced index preload + shfl-broadcast; f32 RMW accumulate into out.

__global__ __launch_bounds__(256)
void gather_mean_add_f32(const __half2* __restrict__ feat, const int* __restrict__ row_ptr,
                         const int* __restrict__ csr_src, const float* __restrict__ deg_inv,
                         float* __restrict__ out) {
    const float4* feat4 = (const float4*)feat;
    const int lane = threadIdx.x & 63;
    const int g = lane >> 4;          // edge slot 0..3
    const int s = lane & 15;          // 16B chunk within row
    const int n = blockIdx.x * 4 + (threadIdx.x >> 6);
    const int beg = row_ptr[n];
    const int end = row_ptr[n + 1];
    float2 acc[4] = {};

    int idx = (beg + lane < end) ? csr_src[beg + lane] : 0;
    int base = beg;
    while (base < end) {
        int cnt = end - base;
        if (cnt > 64) cnt = 64;
        const int nbase = base + 64;
        int nidx = (nbase + lane < end) ? csr_src[nbase + lane] : 0;

        int it = 0;
        for (; it + 16 <= cnt; it += 16) {
            int s0 = __shfl(idx, it + g);
            int s1 = __shfl(idx, it + 4 + g);
            int s2 = __shfl(idx, it + 8 + g);
            int s3 = __shfl(idx, it + 12 + g);
            float4 v0 = feat4[(size_t)s0 * 16 + s];
            float4 v1 = feat4[(size_t)s1 * 16 + s];
            float4 v2 = feat4[(size_t)s2 * 16 + s];
            float4 v3 = feat4[(size_t)s3 * 16 + s];
            add_row(v0, acc);
            add_row(v1, acc);
            add_row(v2, acc);
            add_row(v3, acc);
        }
        for (; it + 4 <= cnt; it += 4) {
            int s0 = __shfl(idx, it + g);
            float4 v0 = feat4[(size_t)s0 * 16 + s];
            add_row(v0, acc);
        }
        if (it < cnt) {
            int s0 = __shfl(idx, it + g);
            if (g < cnt - it) {
                float4 v0 = feat4[(size_t)s0 * 16 + s];
                add_row(v0, acc);
            }
        }
        idx = nidx;
        base = nbase;
    }

    #pragma unroll
    for (int j = 0; j < 4; ++j) {
        acc[j].x += __shfl_xor(acc[j].x, 16);
        acc[j].y += __shfl_xor(acc[j].y, 16);
        acc[j].x += __shfl_xor(acc[j].x, 32);
        acc[j].y += __shfl_xor(acc[j].y, 32);
    }
    if (g == 0) {
        float di = deg_inv[n];
        float4* orow = (float4*)(out + (size_t)n * 128);
        float4 o0 = orow[s * 2];
        float4 o1 = orow[s * 2 + 1];
        o0.x += acc[0].x * di; o0.y += acc[0].y * di;
        o0.z += acc[1].x * di; o0.w += acc[1].y * di;
        o1.x += acc[2].x * di; o1.y += acc[2].y * di;
        o1.z += acc[3].x * di; o1.w += acc[3].y * di;
        orow[s * 2] = o0;
        orow[s * 2 + 1] = o1;
    }
}

// ---------------- fused gather + 2-layer MFMA GEMM ---------------------------
// One kernel, per 16-node tile:
//   phase G: 8 waves gather fp16 means of the tile's 16 nodes into ldsA
//            (wave w -> nodes w*2, w*2+1; indices preloaded lane-parallel)
//   phase 1: h(16x256) = relu(mean@Wl1^T + xb@Wr1^T + b1) via MFMA
//            (wave w owns h cols [w*32, w*32+32)), staged fp16 into ldsH
//   phase 2: P(16x128) = h@Wl2^T ; OUT(16x128) = h@Wr2^T + b2
//            (wave w owns 16 cols of P and 16 cols of OUT)
// mean1 never touches global memory; 2 barriers/tile, single-buffered LDS.
// mfma_f32_16x16x32_f16 layouts (verified):
//   A frag: lane holds A[m = lane&15][k = kc*32 + (lane>>4)*8 + j]
//   B frag: lane holds W[n = lane&15][k]  (W row-major [J,K])
//   C/D:    col = lane&15 (n), row = (lane>>4)*4 + reg
// ldsA pad 136 halves (272B = 68 banks stride -> 2-way, free);
// ldsH pad 264 halves (528B = 132 banks stride -> 2-way, free).

__global__ __launch_bounds__(512, 2)
void sage_fused(const __half* __restrict__ xb,
                const __half* __restrict__ Wl1h, const __half* __restrict__ Wr1h,
                const float* __restrict__ bias1,
                const __half* __restrict__ B20, const __half* __restrict__ B21,
                const float* __restrict__ bias2,
                const int* __restrict__ row_ptr, const int* __restrict__ csr_src,
                const float* __restrict__ deg_inv,
                __half* __restrict__ P, float* __restrict__ out) {
    __shared__ __half ldsA[16][136];
    __shared__ __half ldsH[16][264];
    const float4* feat4 = (const float4*)xb;
    const int lane = threadIdx.x & 63;
    const int wave = threadIdx.x >> 6;      // 0..7
    const int quad = lane >> 4;             // edge slot in gather / row group in mfma
    const int l16 = lane & 15;
    const int koff = quad * 8;

    // ---- per-block B fragments ----
    // layer 1: wave owns h cols [wave*32, wave*32+32)
    f16x8 bf1[2][4][2];
    #pragma unroll
    for (int p = 0; p < 2; ++p) {
        const __half* __restrict__ B = p ? Wr1h : Wl1h;
        #pragma unroll
        for (int kc = 0; kc < 4; ++kc)
            #pragma unroll
            for (int nt = 0; nt < 2; ++nt)
                bf1[p][kc][nt] = *(const f16x8*)(
                    B + (size_t)(wave * 32 + nt * 16 + l16) * D_IN + kc * 32 + koff);
    }
    float bv1[2];
    #pragma unroll
    for (int nt = 0; nt < 2; ++nt) bv1[nt] = bias1[wave * 32 + nt * 16 + l16];

    // layer 2: wave owns P cols [wave*16,+16) and OUT cols [wave*16,+16)
    f16x8 bf20[8], bf21[8];
    #pragma unroll
    for (int kc = 0; kc < 8; ++kc) {
        size_t brow = (size_t)(wave * 16 + l16) * D_HID + kc * 32 + koff;
        bf20[kc] = *(const f16x8*)(B20 + brow);
        bf21[kc] = *(const f16x8*)(B21 + brow);
    }
    float bv2 = bias2[wave * 16 + l16];

    for (int tile = blockIdx.x; tile < NTILES; tile += gridDim.x) {
        // ---- prefetch xb A-frags (lin_r term) so they fly under the gather ----
        f16x8 ax[4];
        const size_t arow = (size_t)(tile * 16 + l16) * D_IN + koff;
        #pragma unroll
        for (int kc = 0; kc < 4; ++kc)
            ax[kc] = *(const f16x8*)(xb + arow + kc * 32);

        // ---- phase G: gather means for nodes [tile*16 + wave*2, +2) ----
        {
            const int nb = tile * 16 + wave * 2;
            int rp = row_ptr[nb + (lane < 2 ? lane : 2)];
            float dv = (lane < 2) ? deg_inv[nb + lane] : 0.f;
            const int spanBeg = __shfl(rp, 0);
            const int spanEnd = __shfl(rp, 2);
            // preload up to 128 edge indices (2-node span; mean 32, >128 ~never)
            int i0 = (spanBeg + lane < spanEnd) ? csr_src[spanBeg + lane] : 0;
            int i1 = (spanBeg + 64 + lane < spanEnd) ? csr_src[spanBeg + 64 + lane] : 0;

            #pragma unroll
            for (int i = 0; i < 2; ++i) {
                const int b = __shfl(rp, i);
                const int e = __shfl(rp, i + 1);
                float2 acc[4] = {};
                if (e - spanBeg <= 128) {       // fast: indices already in regs
                    const int off = b - spanBeg;
                    const int cnt = e - b;
                    int it = 0;
                    for (; it + 16 <= cnt; it += 16) {
                        int p0 = off + it + quad;
                        int p1 = p0 + 4, p2 = p0 + 8, p3 = p0 + 12;
                        int a0 = __shfl(i0, p0 & 63), b0 = __shfl(i1, p0 & 63);
                        int a1 = __shfl(i0, p1 & 63), b1 = __shfl(i1, p1 & 63);
                        int a2 = __shfl(i0, p2 & 63), b2 = __shfl(i1, p2 & 63);
                        int a3 = __shfl(i0, p3 & 63), b3 = __shfl(i1, p3 & 63);
                        int s0 = p0 < 64 ? a0 : b0;
                        int s1 = p1 < 64 ? a1 : b1;
                        int s2 = p2 < 64 ? a2 : b2;
                        int s3 = p3 < 64 ? a3 : b3;
                        float4 v0 = feat4[(size_t)s0 * 16 + l16];
                        float4 v1 = feat4[(size_t)s1 * 16 + l16];
                        float4 v2 = feat4[(size_t)s2 * 16 + l16];
                        float4 v3 = feat4[(size_t)s3 * 16 + l16];
                        add_row(v0, acc);
                        add_row(v1, acc);
                        add_row(v2, acc);
                        add_row(v3, acc);
                    }
                    for (; it + 4 <= cnt; it += 4) {
                        int p0 = off + it + quad;
                        int a0 = __shfl(i0, p0 & 63), b0 = __shfl(i1, p0 & 63);
                        int s0 = p0 < 64 ? a0 : b0;
                        float4 v0 = feat4[(size_t)s0 * 16 + l16];
                        add_row(v0, acc);
                    }
                    if (it < cnt) {
                        int p0 = off + it + quad;
                        int a0 = __shfl(i0, p0 & 63), b0 = __shfl(i1, p0 & 63);
                        int s0 = p0 < 64 ? a0 : b0;
                        if (quad < cnt - it) {
                            float4 v0 = feat4[(size_t)s0 * 16 + l16];
                            add_row(v0, acc);
                        }
                    }
                } else {                         // rare: direct index loads
                    int it = b;
                    for (; it + 16 <= e; it += 16) {
                        int s0 = csr_src[it + quad];
                        int s1 = csr_src[it + 4 + quad];
                        int s2 = csr_src[it + 8 + quad];
                        int s3 = csr_src[it + 12 + quad];
                        float4 v0 = feat4[(size_t)s0 * 16 + l16];
                        float4 v1 = feat4[(size_t)s1 * 16 + l16];
                        float4 v2 = feat4[(size_t)s2 * 16 + l16];
                        float4 v3 = feat4[(size_t)s3 * 16 + l16];
                        add_row(v0, acc);
                        add_row(v1, acc);
                        add_row(v2, acc);
                        add_row(v3, acc);
                    }
                    for (; it + 4 <= e; it += 4) {
                        int s0 = csr_src[it + quad];
                        float4 v0 = feat4[(size_t)s0 * 16 + l16];
                        add_row(v0, acc);
                    }
                    if (it < e) {
                        if (quad < e - it) {
                            int s0 = csr_src[it + quad];
                            float4 v0 = feat4[(size_t)s0 * 16 + l16];
                            add_row(v0, acc);
                        }
                    }
                }
                #pragma unroll
                for (int j = 0; j < 4; ++j) {
                    acc[j].x += __shfl_xor(acc[j].x, 16);
                    acc[j].y += __shfl_xor(acc[j].y, 16);
                    acc[j].x += __shfl_xor(acc[j].x, 32);
                    acc[j].y += __shfl_xor(acc[j].y, 32);
                }
                if (quad == 0) {
                    float di = __shfl(dv, i);
                    float4 o;
                    __half2* op = (__half2*)&o;
                    op[0] = __float22half2_rn(make_float2(acc[0].x * di, acc[0].y * di));
                    op[1] = __float22half2_rn(make_float2(acc[1].x * di, acc[1].y * di));
                    op[2] = __float22half2_rn(make_float2(acc[2].x * di, acc[2].y * di));
                    op[3] = __float22half2_rn(make_float2(acc[3].x * di, acc[3].y * di));
                    *(float4*)&ldsA[wave * 2 + i][l16 * 8] = o;
                }
            }
        }
        __syncthreads();   // ldsA complete; prior tile fully consumed

        // ---- phase 1: h = relu(mean@Wl1^T + xb@Wr1^T + b1) ----
        f32x4 acc1[2] = {};
        #pragma unroll
        for (int kc = 0; kc < 4; ++kc) {
            f16x8 am = *(const f16x8*)&ldsA[l16][kc * 32 + koff];
            #pragma unroll
            for (int nt = 0; nt < 2; ++nt) {
                acc1[nt] = __builtin_amdgcn_mfma_f32_16x16x32_f16(
                    am, bf1[0][kc][nt], acc1[nt], 0, 0, 0);
                acc1[nt] = __builtin_amdgcn_mfma_f32_16x16x32_f16(
                    ax[kc], bf1[1][kc][nt], acc1[nt], 0, 0, 0);
            }
        }
        #pragma unroll
        for (int nt = 0; nt < 2; ++nt) {
            int col = wave * 32 + nt * 16 + l16;
            #pragma unroll
            for (int r = 0; r < 4; ++r)
                ldsH[quad * 4 + r][col] =
                    __float2half(fmaxf(acc1[nt][r] + bv1[nt], 0.f));
        }
        __syncthreads();   // ldsH complete; ldsA free for next tile

        // ---- phase 2: P = h@Wl2^T ; OUT = h@Wr2^T + b2 ----
        f32x4 acc20 = {}, acc21 = {};
        #pragma unroll
        for (int kc = 0; kc < 8; ++kc) {
            f16x8 a2 = *(const f16x8*)&ldsH[l16][kc * 32 + koff];
            acc20 = __builtin_amdgcn_mfma_f32_16x16x32_f16(a2, bf20[kc], acc20, 0, 0, 0);
            acc21 = __builtin_amdgcn_mfma_f32_16x16x32_f16(a2, bf21[kc], acc21, 0, 0, 0);
        }
        const int col = wave * 16 + l16;
        #pragma unroll
        for (int r = 0; r < 4; ++r) {
            int row = tile * 16 + quad * 4 + r;
            P[(size_t)row * D_OUT + col] = __float2half(acc20[r]);
            out[(size_t)row * D_OUT + col] = acc21[r] + bv2;
        }
    }
}

extern "C" void kernel_launch(void* const* d_in, const int* in_sizes, int n_in,
                              void* d_out, int out_size, void* d_ws, size_t ws_size,
                              hipStream_t stream) {
    const float* x   = (const float*)d_in[0];
    const float* Wl1 = (const float*)d_in[1];
    const float* bl1 = (const float*)d_in[2];
    const float* Wr1 = (const float*)d_in[3];
    const float* Wl2 = (const float*)d_in[4];
    const float* bl2 = (const float*)d_in[5];
    const float* Wr2 = (const float*)d_in[6];
    const int*   ei  = (const int*)d_in[7];
    const int* src = ei;              // edge_index[0]
    const int* dst = ei + N_EDGES;    // edge_index[1]
    float* out = (float*)d_out;

    // Workspace layout, 256B-aligned slabs
    char* w = (char*)d_ws;
    auto alloc = [&](size_t bytes) {
        char* r = w;
        w += (bytes + 255) & ~(size_t)255;
        return r;
    };
    int*     deg       = (int*)alloc((size_t)N_NODES * 4);
    int*     row_ptr   = (int*)alloc((size_t)(N_NODES + 1) * 4);
    int*     rank      = (int*)alloc((size_t)N_EDGES * 4);
    int*     partial   = (int*)alloc(NCHUNK * 4);
    int*     csr_src   = (int*)alloc((size_t)N_EDGES * 4);
    float*   deg_inv   = (float*)alloc((size_t)N_NODES * 4);
    __half2* xb        = (__half2*)alloc((size_t)N_NODES * 64 * 4);   // x fp16
    __half2* pb        = (__half2*)alloc((size_t)N_NODES * 64 * 4);   // h@Wl2^T fp16
    __half*  wl1h      = (__half*)alloc(4 * 32768 * 2);
    __half*  wr1h = wl1h + 32768;
    __half*  wl2h = wr1h + 32768;
    __half*  wr2h = wl2h + 32768;

    // Fused prep: x->fp16, weights->fp16, deg=0 (one dispatch)
    prep_kernel<<<3337, 256, 0, stream>>>(x, (__half*)xb, Wl1, Wr1, Wl2, Wr2,
        wl1h, wr1h, wl2h, wr2h, deg);

    // CSR build
    deg_rank_kernel<<<(N_EDGES + 255) / 256, 256, 0, stream>>>(dst, deg, rank);
    chunk_sum<<<NCHUNK, 256, 0, stream>>>(deg, partial);
    scatter_scan<<<NCHUNK, 256, 0, stream>>>(deg, partial, row_ptr, deg_inv);
    fill_csr<<<(N_EDGES + 255) / 256, 256, 0, stream>>>(src, dst, rank, row_ptr, csr_src);

    // Fused: gather mean(x) -> layer1 -> layer2 (P = h@Wl2^T, out = h@Wr2^T + b2)
    sage_fused<<<FUSED_GRID, 512, 0, stream>>>(
        (const __half*)xb, wl1h, wr1h, bl1, wl2h, wr2h, bl2,
        row_ptr, csr_src, deg_inv, (__half*)pb, out);

    // out += mean(P)
    gather_mean_add_f32<<<12500, 256, 0, stream>>>(pb, row_ptr, csr_src, deg_inv, out);
}

// Round 3
// 248.859 us; speedup vs baseline: 1.0477x; 1.0477x over previous
//
#include <hip/hip_runtime.h>
#include <hip/hip_fp16.h>

#define N_NODES 50000
#define N_EDGES 800000
#define D_IN 128
#define D_HID 256
#define D_OUT 128
#define NCHUNK 196   // ceil(N_NODES / 256)
#define NTILES 3125  // N_NODES / 16 exact
#define GEMM_GRID 512

typedef _Float16 f16x8 __attribute__((ext_vector_type(8)));
typedef float f32x4 __attribute__((ext_vector_type(4)));

// ---------------- fused prep: zero_deg + cvt x + cvt weights ------------------
// 16B/lane vectorized: blocks [0,3125): xb; [3125,3141): 4 weight mats;
// [3141,3337): zero deg.

__device__ __forceinline__ void cvt8(const float* __restrict__ src,
                                     __half* __restrict__ dstp, int i) {
    const float4* s4 = (const float4*)src;
    float4 a = s4[i * 2];
    float4 b = s4[i * 2 + 1];
    float4 o;
    __half2* op = (__half2*)&o;
    op[0] = __float22half2_rn(make_float2(a.x, a.y));
    op[1] = __float22half2_rn(make_float2(a.z, a.w));
    op[2] = __float22half2_rn(make_float2(b.x, b.y));
    op[3] = __float22half2_rn(make_float2(b.z, b.w));
    ((float4*)dstp)[i] = o;
}

__global__ __launch_bounds__(256)
void prep_kernel(const float* __restrict__ x, __half* __restrict__ xb,
                 const float* __restrict__ Wl1, const float* __restrict__ Wr1,
                 const float* __restrict__ Wl2, const float* __restrict__ Wr2,
                 __half* __restrict__ wl1h, __half* __restrict__ wr1h,
                 __half* __restrict__ wl2h, __half* __restrict__ wr2h,
                 int* __restrict__ deg) {
    int b = blockIdx.x;
    if (b < 3125) {
        int i = b * 256 + threadIdx.x;            // 800000 threads x 8 floats
        cvt8(x, xb, i);
    } else if (b < 3141) {
        int i = (b - 3125) * 256 + threadIdx.x;   // 4096 threads x 8 floats/mat
        cvt8(Wl1, wl1h, i);
        cvt8(Wr1, wr1h, i);
        cvt8(Wl2, wl2h, i);
        cvt8(Wr2, wr2h, i);
    } else {
        int i = (b - 3141) * 256 + threadIdx.x;
        if (i < N_NODES) deg[i] = 0;
    }
}

// ---------------- CSR build: rank-split (atomic pass separated from scatter) --

__global__ void deg_rank_kernel(const int* __restrict__ dst, int* __restrict__ deg,
                                int* __restrict__ rank) {
    int i = blockIdx.x * blockDim.x + threadIdx.x;
    if (i < N_EDGES) rank[i] = atomicAdd(&deg[dst[i]], 1);
}

__global__ void chunk_sum(const int* __restrict__ deg, int* __restrict__ partial) {
    __shared__ int s[256];
    int i = blockIdx.x * 256 + threadIdx.x;
    s[threadIdx.x] = (i < N_NODES) ? deg[i] : 0;
    __syncthreads();
    for (int off = 128; off > 0; off >>= 1) {
        if (threadIdx.x < off) s[threadIdx.x] += s[threadIdx.x + off];
        __syncthreads();
    }
    if (threadIdx.x == 0) partial[blockIdx.x] = s[0];
}

// Per-chunk scan with integrated cross-chunk base.
__global__ void scatter_scan(const int* __restrict__ deg, const int* __restrict__ partial,
                             int* __restrict__ row_ptr, float* __restrict__ deg_inv) {
    __shared__ int s[256];
    __shared__ int base_s;
    const int tid = threadIdx.x;
    const int bid = blockIdx.x;
    s[tid] = (tid < bid) ? partial[tid] : 0;
    __syncthreads();
    for (int off = 128; off > 0; off >>= 1) {
        if (tid < off) s[tid] += s[tid + off];
        __syncthreads();
    }
    if (tid == 0) base_s = s[0];
    __syncthreads();
    int i = bid * 256 + tid;
    int v = (i < N_NODES) ? deg[i] : 0;
    s[tid] = v;
    __syncthreads();
    for (int off = 1; off < 256; off <<= 1) {
        int t = (tid >= off) ? s[tid - off] : 0;
        __syncthreads();
        s[tid] += t;
        __syncthreads();
    }
    if (i < N_NODES) {
        int rp = base_s + s[tid] - v;   // exclusive scan value
        row_ptr[i] = rp;
        deg_inv[i] = 1.0f / fmaxf((float)v, 1.0f);
        if (i == N_NODES - 1) row_ptr[N_NODES] = N_EDGES;
    }
}

// Atomic-free scatter: position = row_ptr[dst] + rank.
__global__ void fill_csr(const int* __restrict__ src, const int* __restrict__ dst,
                         const int* __restrict__ rank, const int* __restrict__ row_ptr,
                         int* __restrict__ csr_src) {
    int e = blockIdx.x * blockDim.x + threadIdx.x;
    if (e < N_EDGES) {
        csr_src[row_ptr[dst[e]] + rank[e]] = src[e];
    }
}

// ---------------- mean aggregation (full-TLP standalone kernels) -------------
// coalesced index preload (1 lane-parallel csr_src load per 64 edges,
// distributed via __shfl); packed float2 accumulation.

__device__ __forceinline__ void add_row(const float4& v, float2 (&acc)[4]) {
    const __half2* hp = (const __half2*)&v;
    #pragma unroll
    for (int j = 0; j < 4; ++j) {
        float2 f = __half22float2(hp[j]);
        acc[j].x += f.x;
        acc[j].y += f.y;
    }
}

template<bool ACCUM_F32>
__device__ __forceinline__ void gather_core(const __half2* __restrict__ feat,
                                            const int* __restrict__ row_ptr,
                                            const int* __restrict__ csr_src,
                                            const float* __restrict__ deg_inv,
                                            __half2* __restrict__ outh,
                                            float* __restrict__ outf) {
    const float4* feat4 = (const float4*)feat;
    const int lane = threadIdx.x & 63;
    const int g = lane >> 4;          // edge slot 0..3
    const int s = lane & 15;          // 16B chunk within row
    const int n = blockIdx.x * 4 + (threadIdx.x >> 6);
    const int beg = row_ptr[n];
    const int end = row_ptr[n + 1];
    float2 acc[4] = {};

    int idx = (beg + lane < end) ? csr_src[beg + lane] : 0;
    int base = beg;
    while (base < end) {
        int cnt = end - base;
        if (cnt > 64) cnt = 64;
        const int nbase = base + 64;
        int nidx = (nbase + lane < end) ? csr_src[nbase + lane] : 0;

        int it = 0;
        for (; it + 16 <= cnt; it += 16) {  // 4 independent 4-row loads in flight
            int s0 = __shfl(idx, it + g);
            int s1 = __shfl(idx, it + 4 + g);
            int s2 = __shfl(idx, it + 8 + g);
            int s3 = __shfl(idx, it + 12 + g);
            float4 v0 = feat4[(size_t)s0 * 16 + s];
            float4 v1 = feat4[(size_t)s1 * 16 + s];
            float4 v2 = feat4[(size_t)s2 * 16 + s];
            float4 v3 = feat4[(size_t)s3 * 16 + s];
            add_row(v0, acc);
            add_row(v1, acc);
            add_row(v2, acc);
            add_row(v3, acc);
        }
        for (; it + 4 <= cnt; it += 4) {
            int s0 = __shfl(idx, it + g);
            float4 v0 = feat4[(size_t)s0 * 16 + s];
            add_row(v0, acc);
        }
        if (it < cnt) {                   // masked tail (1..3 edges)
            int s0 = __shfl(idx, it + g);
            if (g < cnt - it) {
                float4 v0 = feat4[(size_t)s0 * 16 + s];
                add_row(v0, acc);
            }
        }
        idx = nidx;
        base = nbase;
    }

    #pragma unroll
    for (int j = 0; j < 4; ++j) {
        acc[j].x += __shfl_xor(acc[j].x, 16);
        acc[j].y += __shfl_xor(acc[j].y, 16);
        acc[j].x += __shfl_xor(acc[j].x, 32);
        acc[j].y += __shfl_xor(acc[j].y, 32);
    }
    if (g == 0) {
        float di = deg_inv[n];
        if (ACCUM_F32) {
            float4* orow = (float4*)(outf + (size_t)n * 128);
            float4 o0 = orow[s * 2];
            float4 o1 = orow[s * 2 + 1];
            o0.x += acc[0].x * di; o0.y += acc[0].y * di;
            o0.z += acc[1].x * di; o0.w += acc[1].y * di;
            o1.x += acc[2].x * di; o1.y += acc[2].y * di;
            o1.z += acc[3].x * di; o1.w += acc[3].y * di;
            orow[s * 2] = o0;
            orow[s * 2 + 1] = o1;
        } else {
            float4 o;
            __half2* op = (__half2*)&o;
            op[0] = __float22half2_rn(make_float2(acc[0].x * di, acc[0].y * di));
            op[1] = __float22half2_rn(make_float2(acc[1].x * di, acc[1].y * di));
            op[2] = __float22half2_rn(make_float2(acc[2].x * di, acc[2].y * di));
            op[3] = __float22half2_rn(make_float2(acc[3].x * di, acc[3].y * di));
            ((float4*)(outh + (size_t)n * 64))[s] = o;
        }
    }
}

__global__ __launch_bounds__(256)
void gather_mean_h(const __half2* __restrict__ feat, const int* __restrict__ row_ptr,
                   const int* __restrict__ csr_src, const float* __restrict__ deg_inv,
                   __half2* __restrict__ outv) {
    gather_core<false>(feat, row_ptr, csr_src, deg_inv, outv, nullptr);
}

__global__ __launch_bounds__(256)
void gather_mean_add_f32(const __half2* __restrict__ feat, const int* __restrict__ row_ptr,
                         const int* __restrict__ csr_src, const float* __restrict__ deg_inv,
                         float* __restrict__ out) {
    gather_core<true>(feat, row_ptr, csr_src, deg_inv, nullptr, out);
}

// ---------------- fused MFMA GEMM v2: 8-wave column split --------------------
// Per 16-row tile (512 threads = 8 waves, 2 barriers/tile):
//   phase 1: h(16x256) = relu(mean1@Wl1^T + xb@Wr1^T + b1); wave w owns h cols
//            [w*32, w*32+32). A-frags read straight from global (16 rows x 256B,
//            L2-hot, 8-way redundant across waves - cheap). h staged fp16 in LDS.
//   phase 2: P(16x128) = h@Wl2^T ; OUT(16x128) = h@Wr2^T + b2; wave w owns
//            16 cols of each.
// Per-wave register state ~128 VGPR of fragments (4x less than v1) ->
// __launch_bounds__(512,2) keeps VGPR<=256, 2 waves/SIMD.
// mfma_f32_16x16x32_f16 layouts (verified R4..R11 + round-2 numerics):
//   A frag: lane holds A[m = lane&15][k = kc*32 + (lane>>4)*8 + j]
//   B frag: lane holds W[n = lane&15][k]  (W row-major [J,K])
//   C/D:    col = lane&15 (n), row = (lane>>4)*4 + reg

#define HPAD 264

__global__ __launch_bounds__(512, 2)
void gemm_fused2(const __half* __restrict__ Aa,  // mean1 fp16 [N,128]
                 const __half* __restrict__ Ab,  // xb fp16 [N,128]
                 const __half* __restrict__ Wl1h, const __half* __restrict__ Wr1h,
                 const float* __restrict__ bias1,
                 const __half* __restrict__ B20, const __half* __restrict__ B21,
                 const float* __restrict__ bias2,
                 __half* __restrict__ P, float* __restrict__ out) {
    __shared__ __half ldsH[16][HPAD];
    const int lane = threadIdx.x & 63;
    const int wave = threadIdx.x >> 6;      // 0..7
    const int quad = lane >> 4;
    const int l16 = lane & 15;
    const int koff = quad * 8;

    // layer 1 B-frags: wave owns h cols [wave*32, +32)
    f16x8 bf1[2][4][2];
    #pragma unroll
    for (int p = 0; p < 2; ++p) {
        const __half* __restrict__ B = p ? Wr1h : Wl1h;
        #pragma unroll
        for (int kc = 0; kc < 4; ++kc)
            #pragma unroll
            for (int nt = 0; nt < 2; ++nt)
                bf1[p][kc][nt] = *(const f16x8*)(
                    B + (size_t)(wave * 32 + nt * 16 + l16) * D_IN + kc * 32 + koff);
    }
    float bv1[2];
    #pragma unroll
    for (int nt = 0; nt < 2; ++nt) bv1[nt] = bias1[wave * 32 + nt * 16 + l16];

    // layer 2 B-frags: wave owns P/OUT cols [wave*16, +16)
    f16x8 bf20[8], bf21[8];
    #pragma unroll
    for (int kc = 0; kc < 8; ++kc) {
        size_t brow = (size_t)(wave * 16 + l16) * D_HID + kc * 32 + koff;
        bf20[kc] = *(const f16x8*)(B20 + brow);
        bf21[kc] = *(const f16x8*)(B21 + brow);
    }
    float bv2 = bias2[wave * 16 + l16];

    const int g = gridDim.x;

    auto loadA = [&](int t, f16x8 (&am)[4], f16x8 (&ax)[4]) {
        const size_t arow = (size_t)(t * 16 + l16) * D_IN + koff;
        #pragma unroll
        for (int kc = 0; kc < 4; ++kc) {
            am[kc] = *(const f16x8*)(Aa + arow + kc * 32);
            ax[kc] = *(const f16x8*)(Ab + arow + kc * 32);
        }
    };

    auto step = [&](int tile, const f16x8 (&am)[4], const f16x8 (&ax)[4]) {
        // ---- phase 1: h = relu(mean@Wl1^T + xb@Wr1^T + b1) ----
        f32x4 acc1[2] = {};
        #pragma unroll
        for (int kc = 0; kc < 4; ++kc)
            #pragma unroll
            for (int nt = 0; nt < 2; ++nt) {
                acc1[nt] = __builtin_amdgcn_mfma_f32_16x16x32_f16(
                    am[kc], bf1[0][kc][nt], acc1[nt], 0, 0, 0);
                acc1[nt] = __builtin_amdgcn_mfma_f32_16x16x32_f16(
                    ax[kc], bf1[1][kc][nt], acc1[nt], 0, 0, 0);
            }
        __syncthreads();   // previous tile's phase 2 done reading ldsH
        #pragma unroll
        for (int nt = 0; nt < 2; ++nt) {
            int col = wave * 32 + nt * 16 + l16;
            #pragma unroll
            for (int r = 0; r < 4; ++r)
                ldsH[quad * 4 + r][col] =
                    __float2half(fmaxf(acc1[nt][r] + bv1[nt], 0.f));
        }
        __syncthreads();   // ldsH complete
        // ---- phase 2: P = h@Wl2^T ; OUT = h@Wr2^T + b2 ----
        f32x4 acc20 = {}, acc21 = {};
        #pragma unroll
        for (int kc = 0; kc < 8; ++kc) {
            f16x8 a2 = *(const f16x8*)&ldsH[l16][kc * 32 + koff];
            acc20 = __builtin_amdgcn_mfma_f32_16x16x32_f16(a2, bf20[kc], acc20, 0, 0, 0);
            acc21 = __builtin_amdgcn_mfma_f32_16x16x32_f16(a2, bf21[kc], acc21, 0, 0, 0);
        }
        const int col = wave * 16 + l16;
        #pragma unroll
        for (int r = 0; r < 4; ++r) {
            int row = tile * 16 + quad * 4 + r;
            P[(size_t)row * D_OUT + col] = __float2half(acc20[r]);
            out[(size_t)row * D_OUT + col] = acc21[r] + bv2;
        }
    };

    // grid-stride with double-buffered A prefetch
    f16x8 am0[4], ax0[4], am1[4], ax1[4];
    int tile = blockIdx.x;
    if (tile >= NTILES) return;
    loadA(tile, am0, ax0);
    while (true) {
        if (tile + g < NTILES) loadA(tile + g, am1, ax1);
        step(tile, am0, ax0);
        tile += g;
        if (tile >= NTILES) break;
        if (tile + g < NTILES) loadA(tile + g, am0, ax0);
        step(tile, am1, ax1);
        tile += g;
        if (tile >= NTILES) break;
    }
}

extern "C" void kernel_launch(void* const* d_in, const int* in_sizes, int n_in,
                              void* d_out, int out_size, void* d_ws, size_t ws_size,
                              hipStream_t stream) {
    const float* x   = (const float*)d_in[0];
    const float* Wl1 = (const float*)d_in[1];
    const float* bl1 = (const float*)d_in[2];
    const float* Wr1 = (const float*)d_in[3];
    const float* Wl2 = (const float*)d_in[4];
    const float* bl2 = (const float*)d_in[5];
    const float* Wr2 = (const float*)d_in[6];
    const int*   ei  = (const int*)d_in[7];
    const int* src = ei;              // edge_index[0]
    const int* dst = ei + N_EDGES;    // edge_index[1]
    float* out = (float*)d_out;

    // Workspace layout, 256B-aligned slabs
    char* w = (char*)d_ws;
    auto alloc = [&](size_t bytes) {
        char* r = w;
        w += (bytes + 255) & ~(size_t)255;
        return r;
    };
    int*     deg       = (int*)alloc((size_t)N_NODES * 4);
    int*     row_ptr   = (int*)alloc((size_t)(N_NODES + 1) * 4);
    int*     rank      = (int*)alloc((size_t)N_EDGES * 4);
    int*     partial   = (int*)alloc(NCHUNK * 4);
    int*     csr_src   = (int*)alloc((size_t)N_EDGES * 4);
    float*   deg_inv   = (float*)alloc((size_t)N_NODES * 4);
    __half2* xb        = (__half2*)alloc((size_t)N_NODES * 64 * 4);   // x fp16
    __half2* mean1     = (__half2*)alloc((size_t)N_NODES * 64 * 4);   // mean(x) fp16
    __half2* pb        = (__half2*)alloc((size_t)N_NODES * 64 * 4);   // h@Wl2^T fp16
    __half*  wl1h      = (__half*)alloc(4 * 32768 * 2);
    __half*  wr1h = wl1h + 32768;
    __half*  wl2h = wr1h + 32768;
    __half*  wr2h = wl2h + 32768;

    // Fused prep: x->fp16, weights->fp16, deg=0 (one dispatch)
    prep_kernel<<<3337, 256, 0, stream>>>(x, (__half*)xb, Wl1, Wr1, Wl2, Wr2,
        wl1h, wr1h, wl2h, wr2h, deg);

    // CSR build
    deg_rank_kernel<<<(N_EDGES + 255) / 256, 256, 0, stream>>>(dst, deg, rank);
    chunk_sum<<<NCHUNK, 256, 0, stream>>>(deg, partial);
    scatter_scan<<<NCHUNK, 256, 0, stream>>>(deg, partial, row_ptr, deg_inv);
    fill_csr<<<(N_EDGES + 255) / 256, 256, 0, stream>>>(src, dst, rank, row_ptr, csr_src);

    // Layer 1 aggregation (full TLP: 12500 blocks, wave per node)
    gather_mean_h<<<12500, 256, 0, stream>>>(xb, row_ptr, csr_src, deg_inv, mean1);

    // Fused GEMMs v2: h in LDS; P = h@Wl2^T; out = h@Wr2^T + b2
    gemm_fused2<<<GEMM_GRID, 512, 0, stream>>>(
        (const __half*)mean1, (const __half*)xb, wl1h, wr1h, bl1,
        wl2h, wr2h, bl2, (__half*)pb, out);

    // out += mean(P)
    gather_mean_add_f32<<<12500, 256, 0, stream>>>(pb, row_ptr, csr_src, deg_inv, out);
}